// Round 4
// baseline (246.495 us; speedup 1.0000x reference)
//
#include <hip/hip_runtime.h>
#include <stdint.h>

#define NNODES 200000
#define BNODES 40000
#define DEG    16
#define DFEAT  128
#define DOUT   256
#define NCLS   128
#define TILE   16   // nodes per block (4 per wave)

typedef __attribute__((ext_vector_type(8))) __bf16 bf16x8;
typedef __attribute__((ext_vector_type(4))) float  floatx4;

// round-to-nearest-even fp32 -> bf16 bits
__device__ __forceinline__ uint32_t f2bf(float f) {
  uint32_t x = __float_as_uint(f);
  return ((x + 0x7fffu + ((x >> 16) & 1u)) >> 16) & 0xffffu;
}
__device__ __forceinline__ float bf2f(uint16_t u) {
  return __uint_as_float((uint32_t)u << 16);
}

__global__ __launch_bounds__(256) void cvt_weights(
    const float* __restrict__ W1, const float* __restrict__ W3,
    uint16_t* __restrict__ w1b, uint16_t* __restrict__ w3b) {
  int i = blockIdx.x * 256 + threadIdx.x;
  if (i < DOUT * 2 * DFEAT) w1b[i] = (uint16_t)f2bf(W1[i]);
  if (i < NCLS * DOUT)      w3b[i] = (uint16_t)f2bf(W3[i]);
}

// fp32 feat -> bf16 table, 16 elems/thread, streaming (153 MB total traffic)
__global__ __launch_bounds__(256) void cvt_feat(
    const float* __restrict__ feat, uint16_t* __restrict__ featb) {
  const size_t i = ((size_t)blockIdx.x * 256 + threadIdx.x) * 16;
  const float4 f0 = *(const float4*)(feat + i + 0);
  const float4 f1 = *(const float4*)(feat + i + 4);
  const float4 f2 = *(const float4*)(feat + i + 8);
  const float4 f3 = *(const float4*)(feat + i + 12);
  uint4 p0, p1;
  p0.x = f2bf(f0.x) | (f2bf(f0.y) << 16);
  p0.y = f2bf(f0.z) | (f2bf(f0.w) << 16);
  p0.z = f2bf(f1.x) | (f2bf(f1.y) << 16);
  p0.w = f2bf(f1.z) | (f2bf(f1.w) << 16);
  p1.x = f2bf(f2.x) | (f2bf(f2.y) << 16);
  p1.y = f2bf(f2.z) | (f2bf(f2.w) << 16);
  p1.z = f2bf(f3.x) | (f2bf(f3.y) << 16);
  p1.w = f2bf(f3.z) | (f2bf(f3.w) << 16);
  *(uint4*)(featb + i)     = p0;
  *(uint4*)(featb + i + 8) = p1;
}

template <bool BF16T>
__global__ __launch_bounds__(256, 8) void sage_fused(
    const int* __restrict__ inputs, const int* __restrict__ nbr,
    const float* __restrict__ feat, const uint16_t* __restrict__ featb,
    const uint16_t* __restrict__ w1b, const float* __restrict__ b1,
    const uint16_t* __restrict__ w3b, const float* __restrict__ b3,
    float* __restrict__ out) {
  // TILE=16: embL/lgL alias (8448 B) + hL (8448 B) = 16896 B => 8 blocks/CU
  // (32 waves/CU possible at <=64 VGPR -- the whole point of this round)
  __shared__ __align__(16) unsigned char smemA[TILE * 264 * 2];   // 8448 B
  __shared__ __align__(16) uint16_t hL[TILE][264];                // 8448 B
  uint16_t (*embL)[264] = (uint16_t (*)[264])smemA;
  float    (*lgL)[132]  = (float    (*)[132])smemA;

  const int tid  = threadIdx.x;
  // wave index provably uniform -> neighbor/self id reads become s_loads,
  // and every gathered row gets a pure-SGPR base address (saddr form).
  const int w    = __builtin_amdgcn_readfirstlane(tid >> 6);   // wave 0..3
  const int lane = tid & 63;
  const int quad = lane >> 4;
  const int l16  = lane & 15;

  // ---------------- Phase 1: gather + segment-mean -> emb (bf16 in LDS) ----
  // Full wave per row: 64 lanes x ushort2 (4B) = one 256B bf16 row per VMEM
  // instruction, SGPR base + shared lane voffset => 1 result VGPR per row.
  // A 2-node batch keeps 34 rows (~8.7KB) in flight per wave; no cross-lane
  // reduction needed (lane owns dims 2l,2l+1). Self row read from the bf16
  // table is bit-identical to the old fp32-read-then-round path.
  {
    const int nodeBase = blockIdx.x * TILE + w * 4;
    if constexpr (BF16T) {
      const uint16_t* fb = featb + lane * 2;
#pragma unroll
      for (int p = 0; p < 4; p += 2) {
        const int nA = nodeBase + p, nB = nodeBase + p + 1;
        const int* nbA = nbr + nA * DEG;     // wave-uniform -> s_load
        const int* nbB = nbr + nB * DEG;
        const int sA = inputs[nA], sB = inputs[nB];
        ushort2 rA[16], rB[16];
#pragma unroll
        for (int j = 0; j < 16; ++j)
          rA[j] = *(const ushort2*)(fb + (size_t)nbA[j] * DFEAT);
        const ushort2 svA = *(const ushort2*)(fb + (size_t)sA * DFEAT);
#pragma unroll
        for (int j = 0; j < 16; ++j)
          rB[j] = *(const ushort2*)(fb + (size_t)nbB[j] * DFEAT);
        const ushort2 svB = *(const ushort2*)(fb + (size_t)sB * DFEAT);
        // reduce + write A
        {
          const float sx = (((bf2f(rA[0].x) + bf2f(rA[1].x)) + (bf2f(rA[2].x) + bf2f(rA[3].x)))
                          + ((bf2f(rA[4].x) + bf2f(rA[5].x)) + (bf2f(rA[6].x) + bf2f(rA[7].x))))
                         + (((bf2f(rA[8].x) + bf2f(rA[9].x)) + (bf2f(rA[10].x) + bf2f(rA[11].x)))
                          + ((bf2f(rA[12].x) + bf2f(rA[13].x)) + (bf2f(rA[14].x) + bf2f(rA[15].x))));
          const float sy = (((bf2f(rA[0].y) + bf2f(rA[1].y)) + (bf2f(rA[2].y) + bf2f(rA[3].y)))
                          + ((bf2f(rA[4].y) + bf2f(rA[5].y)) + (bf2f(rA[6].y) + bf2f(rA[7].y))))
                         + (((bf2f(rA[8].y) + bf2f(rA[9].y)) + (bf2f(rA[10].y) + bf2f(rA[11].y)))
                          + ((bf2f(rA[12].y) + bf2f(rA[13].y)) + (bf2f(rA[14].y) + bf2f(rA[15].y))));
          const int row = w * 4 + p;
          *(uint32_t*)&embL[row][lane * 2]         = (uint32_t)svA.x | ((uint32_t)svA.y << 16);
          *(uint32_t*)&embL[row][DFEAT + lane * 2] = f2bf(sx * 0.0625f) | (f2bf(sy * 0.0625f) << 16);
        }
        // reduce + write B
        {
          const float sx = (((bf2f(rB[0].x) + bf2f(rB[1].x)) + (bf2f(rB[2].x) + bf2f(rB[3].x)))
                          + ((bf2f(rB[4].x) + bf2f(rB[5].x)) + (bf2f(rB[6].x) + bf2f(rB[7].x))))
                         + (((bf2f(rB[8].x) + bf2f(rB[9].x)) + (bf2f(rB[10].x) + bf2f(rB[11].x)))
                          + ((bf2f(rB[12].x) + bf2f(rB[13].x)) + (bf2f(rB[14].x) + bf2f(rB[15].x))));
          const float sy = (((bf2f(rB[0].y) + bf2f(rB[1].y)) + (bf2f(rB[2].y) + bf2f(rB[3].y)))
                          + ((bf2f(rB[4].y) + bf2f(rB[5].y)) + (bf2f(rB[6].y) + bf2f(rB[7].y))))
                         + (((bf2f(rB[8].y) + bf2f(rB[9].y)) + (bf2f(rB[10].y) + bf2f(rB[11].y)))
                          + ((bf2f(rB[12].y) + bf2f(rB[13].y)) + (bf2f(rB[14].y) + bf2f(rB[15].y))));
          const int row = w * 4 + p + 1;
          *(uint32_t*)&embL[row][lane * 2]         = (uint32_t)svB.x | ((uint32_t)svB.y << 16);
          *(uint32_t*)&embL[row][DFEAT + lane * 2] = f2bf(sx * 0.0625f) | (f2bf(sy * 0.0625f) << 16);
        }
      }
    } else {
      // fp32 fallback (workspace too small): full-wave float2 rows, 1 node/batch
      const float* fb = feat + lane * 2;
#pragma unroll
      for (int p = 0; p < 4; ++p) {
        const int node = nodeBase + p;
        const int* nb  = nbr + node * DEG;
        const int self = inputs[node];
        float2 r[16];
#pragma unroll
        for (int j = 0; j < 16; ++j)
          r[j] = *(const float2*)(fb + (size_t)nb[j] * DFEAT);
        const float2 sv = *(const float2*)(fb + (size_t)self * DFEAT);
        const float sx = (((r[0].x + r[1].x) + (r[2].x + r[3].x)) + ((r[4].x + r[5].x) + (r[6].x + r[7].x)))
                       + (((r[8].x + r[9].x) + (r[10].x + r[11].x)) + ((r[12].x + r[13].x) + (r[14].x + r[15].x)));
        const float sy = (((r[0].y + r[1].y) + (r[2].y + r[3].y)) + ((r[4].y + r[5].y) + (r[6].y + r[7].y)))
                       + (((r[8].y + r[9].y) + (r[10].y + r[11].y)) + ((r[12].y + r[13].y) + (r[14].y + r[15].y)));
        const int row = w * 4 + p;
        *(uint32_t*)&embL[row][lane * 2]         = f2bf(sv.x) | (f2bf(sv.y) << 16);
        *(uint32_t*)&embL[row][DFEAT + lane * 2] = f2bf(sx * 0.0625f) | (f2bf(sy * 0.0625f) << 16);
      }
    }
  }
  __syncthreads();

  const int kq = quad * 8;

  // ---------------- Phase 2: h = relu(emb @ W1^T + b1), bf16 -> LDS --------
  // M=16 rows; wave w owns output cols w*64 .. w*64+63
  {
    floatx4 acc[4];
#pragma unroll
    for (int ot = 0; ot < 4; ++ot) {
      floatx4 z = {0.f, 0.f, 0.f, 0.f};
      acc[ot] = z;
    }
#pragma unroll
    for (int kt = 0; kt < 8; ++kt) {
      const int k0 = kt * 32 + kq;
      const bf16x8 a = *(const bf16x8*)&embL[l16][k0];
#pragma unroll
      for (int ot = 0; ot < 4; ++ot) {
        const int o = w * 64 + ot * 16 + l16;
        const bf16x8 b = *(const bf16x8*)(w1b + o * 256 + k0);
        acc[ot] = __builtin_amdgcn_mfma_f32_16x16x32_bf16(a, b, acc[ot], 0, 0, 0);
      }
    }
#pragma unroll
    for (int ot = 0; ot < 4; ++ot) {
      const int o = w * 64 + ot * 16 + l16;
      const float bias = b1[o];
#pragma unroll
      for (int r = 0; r < 4; ++r) {
        float v = acc[ot][r] + bias;
        v = fmaxf(v, 0.f);
        hL[quad * 4 + r][o] = (uint16_t)f2bf(v);
      }
    }
  }
  __syncthreads();

  // ---------------- Phase 3: logits = h @ W3^T + b3 -> LDS fp32 ------------
  // (writes lgL, aliasing embL -- dead after phase 2's barrier)
  {
    floatx4 acc2[2];
#pragma unroll
    for (int ct = 0; ct < 2; ++ct) {
      floatx4 z = {0.f, 0.f, 0.f, 0.f};
      acc2[ct] = z;
    }
#pragma unroll
    for (int kt = 0; kt < 8; ++kt) {
      const int k0 = kt * 32 + kq;
      const bf16x8 a = *(const bf16x8*)&hL[l16][k0];
#pragma unroll
      for (int ct = 0; ct < 2; ++ct) {
        const int c = w * 32 + ct * 16 + l16;
        const bf16x8 b = *(const bf16x8*)(w3b + c * 256 + k0);
        acc2[ct] = __builtin_amdgcn_mfma_f32_16x16x32_bf16(a, b, acc2[ct], 0, 0, 0);
      }
    }
#pragma unroll
    for (int ct = 0; ct < 2; ++ct) {
      const int c = w * 32 + ct * 16 + l16;
      const float bias = b3[c];
#pragma unroll
      for (int r = 0; r < 4; ++r)
        lgL[quad * 4 + r][c] = acc2[ct][r] + bias;
    }
  }
  __syncthreads();

  // ---------------- Phase 4: row L2-normalize + store ----------------------
  {
    const int nr  = tid >> 4;       // node row 0..15
    const int sub = tid & 15;       // 16 threads per row, 8 cols each
    const float* lrow = &lgL[nr][sub * 8];
    float4 v0 = *(const float4*)(lrow + 0);
    float4 v1 = *(const float4*)(lrow + 4);
    float ss = v0.x * v0.x + v0.y * v0.y + v0.z * v0.z + v0.w * v0.w
             + v1.x * v1.x + v1.y * v1.y + v1.z * v1.z + v1.w * v1.w;
    ss += __shfl_xor(ss, 1);
    ss += __shfl_xor(ss, 2);
    ss += __shfl_xor(ss, 4);
    ss += __shfl_xor(ss, 8);
    const float scale = 1.f / fmaxf(sqrtf(ss), 1e-12f);
    v0.x *= scale; v0.y *= scale; v0.z *= scale; v0.w *= scale;
    v1.x *= scale; v1.y *= scale; v1.z *= scale; v1.w *= scale;
    float* op = out + ((size_t)(blockIdx.x * TILE + nr)) * NCLS + sub * 8;
    *(float4*)(op + 0) = v0;
    *(float4*)(op + 4) = v1;
  }
}

extern "C" void kernel_launch(void* const* d_in, const int* in_sizes, int n_in,
                              void* d_out, int out_size, void* d_ws, size_t ws_size,
                              hipStream_t stream) {
  const int*   inputs = (const int*)d_in[0];
  const int*   nbr    = (const int*)d_in[1];
  // d_in[2] segment_ids: regular repeat(arange(B), 16) -> implicit, unused
  const float* feat   = (const float*)d_in[3];
  const float* W1     = (const float*)d_in[4];
  const float* b1     = (const float*)d_in[5];
  const float* W3     = (const float*)d_in[6];
  const float* b3     = (const float*)d_in[7];

  uint16_t* w1b   = (uint16_t*)d_ws;               // 256*256 bf16 = 128 KiB
  uint16_t* w3b   = w1b + DOUT * 2 * DFEAT;        // 128*256 bf16 =  64 KiB
  uint16_t* featb = w3b + NCLS * DOUT;             // 200000*128 bf16 = 51.2 MB

  const size_t need = ((size_t)(DOUT * 2 * DFEAT + NCLS * DOUT)
                     + (size_t)NNODES * DFEAT) * sizeof(uint16_t);

  cvt_weights<<<(DOUT * 2 * DFEAT) / 256, 256, 0, stream>>>(W1, W3, w1b, w3b);
  if (ws_size >= need) {
    cvt_feat<<<(NNODES * DFEAT) / (256 * 16), 256, 0, stream>>>(feat, featb);
    sage_fused<true><<<BNODES / TILE, 256, 0, stream>>>(
        inputs, nbr, feat, featb, w1b, b1, w3b, b3, (float*)d_out);
  } else {
    sage_fused<false><<<BNODES / TILE, 256, 0, stream>>>(
        inputs, nbr, feat, nullptr, w1b, b1, w3b, b3, (float*)d_out);
  }
}

// Round 5
// 238.606 us; speedup vs baseline: 1.0331x; 1.0331x over previous
//
#include <hip/hip_runtime.h>
#include <stdint.h>

#define NNODES 200000
#define BNODES 40000
#define DEG    16
#define DFEAT  128
#define DOUT   256
#define NCLS   128
#define TILE   16   // nodes per block (4 per wave)

#define FEAT_CVT_BLOCKS 6250   // 200000*128 elems / (256 thr * 16 elems)

typedef __attribute__((ext_vector_type(8))) __bf16 bf16x8;
typedef __attribute__((ext_vector_type(4))) float  floatx4;

// round-to-nearest-even fp32 -> bf16 bits
__device__ __forceinline__ uint32_t f2bf(float f) {
  uint32_t x = __float_as_uint(f);
  return ((x + 0x7fffu + ((x >> 16) & 1u)) >> 16) & 0xffffu;
}

// fp32 -> OCP e4m3fn, RTNE, saturating at 448, denormal-correct
__device__ __forceinline__ uint32_t f2fp8(float f) {
  uint32_t u = __float_as_uint(f);
  uint32_t s = (u >> 24) & 0x80u;
  uint32_t a = u & 0x7fffffffu;
  if (a >= 0x43E80000u) return s | 0x7Eu;            // |x| >= 464 -> 448
  if (a < 0x3C800000u) {                             // |x| < 2^-6 -> denormal
    uint32_t q = (uint32_t)rintf(__uint_as_float(a) * 512.0f);  // RTNE, 0..8
    return s | q;                                    // q==8 == 2^-6 exactly
  }
  uint32_t r = a + 0x7FFFFu + ((a >> 20) & 1u);      // RTNE into 3-bit mantissa
  return s | ((r >> 20) - (120u << 3));              // ((e8-120)<<3)|m3
}

// e4m3fn byte -> f32: exponent re-bias via *2^120. Denormal codes decode via
// f32-denormal HW; if FTZ, error <= 0.0137 on ~1.2% of features -> negligible
// after the /16 mean.
__device__ __forceinline__ float fp82f(uint32_t b) {
  uint32_t x = ((b & 0x80u) << 24) | ((b & 0x7Fu) << 20);
  return __uint_as_float(x) * __uint_as_float(0x7B800000u);   // * 2^120
}

// weights-only fallback converter
__global__ __launch_bounds__(256) void cvt_weights(
    const float* __restrict__ W1, const float* __restrict__ W3,
    uint16_t* __restrict__ w1b, uint16_t* __restrict__ w3b) {
  int i = blockIdx.x * 256 + threadIdx.x;
  if (i < DOUT * 2 * DFEAT) w1b[i] = (uint16_t)f2bf(W1[i]);
  if (i < NCLS * DOUT)      w3b[i] = (uint16_t)f2bf(W3[i]);
}

// fused: feat fp32 -> e4m3 table (128 MB traffic) + weights -> bf16
__global__ __launch_bounds__(256) void cvt_all(
    const float* __restrict__ feat, const float* __restrict__ W1,
    const float* __restrict__ W3, uint8_t* __restrict__ featb8,
    uint16_t* __restrict__ w1b, uint16_t* __restrict__ w3b) {
  const int b = blockIdx.x;
  if (b < FEAT_CVT_BLOCKS) {
    const size_t i = ((size_t)b * 256 + threadIdx.x) * 16;
    const float4 f0 = *(const float4*)(feat + i + 0);
    const float4 f1 = *(const float4*)(feat + i + 4);
    const float4 f2 = *(const float4*)(feat + i + 8);
    const float4 f3 = *(const float4*)(feat + i + 12);
    uint4 p;
    p.x = f2fp8(f0.x) | (f2fp8(f0.y) << 8) | (f2fp8(f0.z) << 16) | (f2fp8(f0.w) << 24);
    p.y = f2fp8(f1.x) | (f2fp8(f1.y) << 8) | (f2fp8(f1.z) << 16) | (f2fp8(f1.w) << 24);
    p.z = f2fp8(f2.x) | (f2fp8(f2.y) << 8) | (f2fp8(f2.z) << 16) | (f2fp8(f2.w) << 24);
    p.w = f2fp8(f3.x) | (f2fp8(f3.y) << 8) | (f2fp8(f3.z) << 16) | (f2fp8(f3.w) << 24);
    *(uint4*)(featb8 + i) = p;
  } else {
    const int i = (b - FEAT_CVT_BLOCKS) * 256 + threadIdx.x;
    if (i < DOUT * 2 * DFEAT) w1b[i] = (uint16_t)f2bf(W1[i]);
    if (i < NCLS * DOUT)      w3b[i] = (uint16_t)f2bf(W3[i]);
  }
}

template <bool FP8T>
__global__ __launch_bounds__(256, 6) void sage_fused(
    const int* __restrict__ inputs, const int* __restrict__ nbr,
    const float* __restrict__ feat, const uint8_t* __restrict__ featb8,
    const uint16_t* __restrict__ w1b, const float* __restrict__ b1,
    const uint16_t* __restrict__ w3b, const float* __restrict__ b3,
    float* __restrict__ out) {
  // TILE=16: embL/lgL alias (8448 B) + hL (8448 B) = 16896 B
  __shared__ __align__(16) unsigned char smemA[TILE * 264 * 2];   // 8448 B
  __shared__ __align__(16) uint16_t hL[TILE][264];                // 8448 B
  uint16_t (*embL)[264] = (uint16_t (*)[264])smemA;
  float    (*lgL)[132]  = (float    (*)[132])smemA;

  const int tid  = threadIdx.x;
  const int w    = __builtin_amdgcn_readfirstlane(tid >> 6);   // wave 0..3
  const int lane = tid & 63;
  const int quad = lane >> 4;
  const int l16  = lane & 15;

  // ---------------- Phase 1: gather + segment-mean -> emb (bf16 in LDS) ----
  // fp8 table: row = 128 B. One full-wave uint2 load (8 B/lane) covers FOUR
  // rows per VMEM instruction (lane>>4 = row slot, lane&15 = 8-dim chunk).
  // 4 gather insts + 1 fp32 self inst per node = 5 wave-VMEM/node (vs 17 in
  // r4). Per-lane partial sums over the 4 row-slots, then one 2-step
  // shfl_xor(16/32) butterfly per node combines the slots.
  {
    const int nodeBase = blockIdx.x * TILE + w * 4;
    if constexpr (FP8T) {
      const uint8_t* fb = featb8 + (lane & 15) * 8;   // chunk byte offset
#pragma unroll
      for (int p = 0; p < 4; p += 2) {
        const int nA = nodeBase + p, nB = nodeBase + p + 1;
        const int* nbA = nbr + nA * DEG;     // wave-uniform -> s_load
        const int* nbB = nbr + nB * DEG;
        const int sA = inputs[nA], sB = inputs[nB];
        uint2 gA[4], gB[4];
        // ---- issue both nodes' loads (10 VMEM, ~5 KB in flight) ----------
#pragma unroll
        for (int k = 0; k < 4; ++k) {
          const int i0 = nbA[4 * k + 0], i1 = nbA[4 * k + 1];
          const int i2 = nbA[4 * k + 2], i3 = nbA[4 * k + 3];
          const int lo  = (lane & 16) ? i1 : i0;
          const int hi  = (lane & 16) ? i3 : i2;
          const int rid = (lane & 32) ? hi : lo;       // row slot = lane>>4
          gA[k] = *(const uint2*)(fb + (size_t)rid * DFEAT);
        }
        const float2 svA = *(const float2*)(feat + (size_t)sA * DFEAT + lane * 2);
#pragma unroll
        for (int k = 0; k < 4; ++k) {
          const int i0 = nbB[4 * k + 0], i1 = nbB[4 * k + 1];
          const int i2 = nbB[4 * k + 2], i3 = nbB[4 * k + 3];
          const int lo  = (lane & 16) ? i1 : i0;
          const int hi  = (lane & 16) ? i3 : i2;
          const int rid = (lane & 32) ? hi : lo;
          gB[k] = *(const uint2*)(fb + (size_t)rid * DFEAT);
        }
        const float2 svB = *(const float2*)(feat + (size_t)sB * DFEAT + lane * 2);
        // ---- reduce + write, node A then node B --------------------------
#pragma unroll
        for (int nn = 0; nn < 2; ++nn) {
          const uint2* g = nn ? gB : gA;
          const float2 sv = nn ? svB : svA;
          const int row = w * 4 + p + nn;
          float acc[8] = {0.f, 0.f, 0.f, 0.f, 0.f, 0.f, 0.f, 0.f};
#pragma unroll
          for (int k = 0; k < 4; ++k) {
            const uint32_t lo = g[k].x, hi = g[k].y;
#pragma unroll
            for (int j = 0; j < 4; ++j) {
              acc[j]     += fp82f((lo >> (8 * j)) & 0xffu);
              acc[4 + j] += fp82f((hi >> (8 * j)) & 0xffu);
            }
          }
#pragma unroll
          for (int j = 0; j < 8; ++j) {
            acc[j] += __shfl_xor(acc[j], 16);   // combine row slots 0<->1
            acc[j] += __shfl_xor(acc[j], 32);   // combine row slots {0,1}<->{2,3}
          }
          uint4 mp;
          mp.x = f2bf(acc[0] * 0.0625f) | (f2bf(acc[1] * 0.0625f) << 16);
          mp.y = f2bf(acc[2] * 0.0625f) | (f2bf(acc[3] * 0.0625f) << 16);
          mp.z = f2bf(acc[4] * 0.0625f) | (f2bf(acc[5] * 0.0625f) << 16);
          mp.w = f2bf(acc[6] * 0.0625f) | (f2bf(acc[7] * 0.0625f) << 16);
          *(uint32_t*)&embL[row][lane * 2] = f2bf(sv.x) | (f2bf(sv.y) << 16);
          if (lane < 16)                       // lane == chunk c: dims 8c..8c+7
            *(uint4*)&embL[row][DFEAT + lane * 8] = mp;
        }
      }
    } else {
      // fp32 fallback (workspace too small): full-wave float2 rows
      const float* fb = feat + lane * 2;
#pragma unroll
      for (int p = 0; p < 4; ++p) {
        const int node = nodeBase + p;
        const int* nb  = nbr + node * DEG;
        const int self = inputs[node];
        float2 r[16];
#pragma unroll
        for (int j = 0; j < 16; ++j)
          r[j] = *(const float2*)(fb + (size_t)nb[j] * DFEAT);
        const float2 sv = *(const float2*)(fb + (size_t)self * DFEAT);
        const float sx = (((r[0].x + r[1].x) + (r[2].x + r[3].x)) + ((r[4].x + r[5].x) + (r[6].x + r[7].x)))
                       + (((r[8].x + r[9].x) + (r[10].x + r[11].x)) + ((r[12].x + r[13].x) + (r[14].x + r[15].x)));
        const float sy = (((r[0].y + r[1].y) + (r[2].y + r[3].y)) + ((r[4].y + r[5].y) + (r[6].y + r[7].y)))
                       + (((r[8].y + r[9].y) + (r[10].y + r[11].y)) + ((r[12].y + r[13].y) + (r[14].y + r[15].y)));
        const int row = w * 4 + p;
        *(uint32_t*)&embL[row][lane * 2]         = f2bf(sv.x) | (f2bf(sv.y) << 16);
        *(uint32_t*)&embL[row][DFEAT + lane * 2] = f2bf(sx * 0.0625f) | (f2bf(sy * 0.0625f) << 16);
      }
    }
  }
  __syncthreads();

  const int kq = quad * 8;

  // ---------------- Phase 2: h = relu(emb @ W1^T + b1), bf16 -> LDS --------
  // M=16 rows; wave w owns output cols w*64 .. w*64+63
  {
    floatx4 acc[4];
#pragma unroll
    for (int ot = 0; ot < 4; ++ot) {
      floatx4 z = {0.f, 0.f, 0.f, 0.f};
      acc[ot] = z;
    }
#pragma unroll
    for (int kt = 0; kt < 8; ++kt) {
      const int k0 = kt * 32 + kq;
      const bf16x8 a = *(const bf16x8*)&embL[l16][k0];
#pragma unroll
      for (int ot = 0; ot < 4; ++ot) {
        const int o = w * 64 + ot * 16 + l16;
        const bf16x8 b = *(const bf16x8*)(w1b + o * 256 + k0);
        acc[ot] = __builtin_amdgcn_mfma_f32_16x16x32_bf16(a, b, acc[ot], 0, 0, 0);
      }
    }
#pragma unroll
    for (int ot = 0; ot < 4; ++ot) {
      const int o = w * 64 + ot * 16 + l16;
      const float bias = b1[o];
#pragma unroll
      for (int r = 0; r < 4; ++r) {
        float v = acc[ot][r] + bias;
        v = fmaxf(v, 0.f);
        hL[quad * 4 + r][o] = (uint16_t)f2bf(v);
      }
    }
  }
  __syncthreads();

  // ---------------- Phase 3: logits = h @ W3^T + b3 -> LDS fp32 ------------
  {
    floatx4 acc2[2];
#pragma unroll
    for (int ct = 0; ct < 2; ++ct) {
      floatx4 z = {0.f, 0.f, 0.f, 0.f};
      acc2[ct] = z;
    }
#pragma unroll
    for (int kt = 0; kt < 8; ++kt) {
      const int k0 = kt * 32 + kq;
      const bf16x8 a = *(const bf16x8*)&hL[l16][k0];
#pragma unroll
      for (int ct = 0; ct < 2; ++ct) {
        const int c = w * 32 + ct * 16 + l16;
        const bf16x8 b = *(const bf16x8*)(w3b + c * 256 + k0);
        acc2[ct] = __builtin_amdgcn_mfma_f32_16x16x32_bf16(a, b, acc2[ct], 0, 0, 0);
      }
    }
#pragma unroll
    for (int ct = 0; ct < 2; ++ct) {
      const int c = w * 32 + ct * 16 + l16;
      const float bias = b3[c];
#pragma unroll
      for (int r = 0; r < 4; ++r)
        lgL[quad * 4 + r][c] = acc2[ct][r] + bias;
    }
  }
  __syncthreads();

  // ---------------- Phase 4: row L2-normalize + store ----------------------
  {
    const int nr  = tid >> 4;       // node row 0..15
    const int sub = tid & 15;       // 16 threads per row, 8 cols each
    const float* lrow = &lgL[nr][sub * 8];
    float4 v0 = *(const float4*)(lrow + 0);
    float4 v1 = *(const float4*)(lrow + 4);
    float ss = v0.x * v0.x + v0.y * v0.y + v0.z * v0.z + v0.w * v0.w
             + v1.x * v1.x + v1.y * v1.y + v1.z * v1.z + v1.w * v1.w;
    ss += __shfl_xor(ss, 1);
    ss += __shfl_xor(ss, 2);
    ss += __shfl_xor(ss, 4);
    ss += __shfl_xor(ss, 8);
    const float scale = 1.f / fmaxf(sqrtf(ss), 1e-12f);
    v0.x *= scale; v0.y *= scale; v0.z *= scale; v0.w *= scale;
    v1.x *= scale; v1.y *= scale; v1.z *= scale; v1.w *= scale;
    float* op = out + ((size_t)(blockIdx.x * TILE + nr)) * NCLS + sub * 8;
    *(float4*)(op + 0) = v0;
    *(float4*)(op + 4) = v1;
  }
}

extern "C" void kernel_launch(void* const* d_in, const int* in_sizes, int n_in,
                              void* d_out, int out_size, void* d_ws, size_t ws_size,
                              hipStream_t stream) {
  const int*   inputs = (const int*)d_in[0];
  const int*   nbr    = (const int*)d_in[1];
  // d_in[2] segment_ids: regular repeat(arange(B), 16) -> implicit, unused
  const float* feat   = (const float*)d_in[3];
  const float* W1     = (const float*)d_in[4];
  const float* b1     = (const float*)d_in[5];
  const float* W3     = (const float*)d_in[6];
  const float* b3     = (const float*)d_in[7];

  uint16_t* w1b    = (uint16_t*)d_ws;               // 256*256 bf16 = 128 KiB
  uint16_t* w3b    = w1b + DOUT * 2 * DFEAT;        // 128*256 bf16 =  64 KiB
  uint8_t*  featb8 = (uint8_t*)(w3b + NCLS * DOUT); // 200000*128 e4m3 = 25.6 MB

  const size_t need = (size_t)(DOUT * 2 * DFEAT + NCLS * DOUT) * sizeof(uint16_t)
                    + (size_t)NNODES * DFEAT;

  if (ws_size >= need) {
    cvt_all<<<FEAT_CVT_BLOCKS + (DOUT * 2 * DFEAT) / 256, 256, 0, stream>>>(
        feat, W1, W3, featb8, w1b, w3b);
    sage_fused<true><<<BNODES / TILE, 256, 0, stream>>>(
        inputs, nbr, feat, featb8, w1b, b1, w3b, b3, (float*)d_out);
  } else {
    cvt_weights<<<(DOUT * 2 * DFEAT) / 256, 256, 0, stream>>>(W1, W3, w1b, w3b);
    sage_fused<false><<<BNODES / TILE, 256, 0, stream>>>(
        inputs, nbr, feat, nullptr, w1b, b1, w3b, b3, (float*)d_out);
  }
}